// Round 14
// baseline (202.769 us; speedup 1.0000x reference)
//
#include <hip/hip_runtime.h>

// GRU stacked: G=2 layers, H=2, T=8, B=2097152.
// Round-14 = round-8 (59.2us best: ILP-2, exp2+rcp trans activations,
// epilogue label loads, LDS transpose, NT dense stores) + ONE change:
// the loss reduction is folded into gru_fused via the last-block-done
// pattern (agent-scope atomics; cross-XCD-safe), removing the second
// kernel launch and its latency-bound 1-block reduce.
//   sigma(x') = rcp(1+exp2(x')), x' = -log2(e)*x (scale folded into W);
//   tanh via x' = -2log2(e)*x, 2*sig-1.

typedef float v2f __attribute__((ext_vector_type(2)));
typedef float v4f __attribute__((ext_vector_type(4)));

__device__ __forceinline__ v2f v2(float a, float b) { v2f r; r.x = a; r.y = b; return r; }
__device__ __forceinline__ v2f vbc(float a) { return v2(a, a); }
__device__ __forceinline__ v2f vswap(v2f a) { return __builtin_shufflevector(a, a, 1, 0); }
__device__ __forceinline__ v2f vfma(v2f a, v2f b, v2f c) { return __builtin_elementwise_fma(a, b, c); }

// rcp(1+exp2(y)) per component: 2 exp2 + 2 rcp (trans), saturation-safe.
__device__ __forceinline__ v2f sig2(v2f y) {
    v2f e;
    e.x = __builtin_amdgcn_exp2f(y.x);
    e.y = __builtin_amdgcn_exp2f(y.y);
    const v2f d = e + vbc(1.0f);
    v2f q;
    q.x = __builtin_amdgcn_rcpf(d.x);
    q.y = __builtin_amdgcn_rcpf(d.y);
    return q;
}

// One GRU cell; weights pre-scaled: r/z rows by -log2(e), n rows by -2log2(e).
__device__ __forceinline__ v2f gru_cell(v2f o, v2f h,
    const v2f wihA[3], const v2f wihB[3],
    const v2f whhA[3], const v2f whhB[3], const v2f bpk[3])
{
    const v2f os = vswap(o);
    const v2f hs = vswap(h);
    v2f rin = vfma(wihA[0], o,
              vfma(wihB[0], os,
              vfma(whhA[0], h,
              vfma(whhB[0], hs, bpk[0]))));
    v2f zin = vfma(wihA[1], o,
              vfma(wihB[1], os,
              vfma(whhA[1], h,
              vfma(whhB[1], hs, bpk[1]))));
    v2f gin = vfma(wihA[2], o, vfma(wihB[2], os, bpk[2]));   // pre-scaled
    v2f ghn = vfma(whhA[2], h, whhB[2] * hs);                // pre-scaled

    const v2f r = sig2(rin);
    const v2f z = sig2(zin);
    const v2f q = sig2(vfma(r, ghn, gin));
    const v2f n = vfma(vbc(2.0f), q, vbc(-1.0f));            // tanh
    return vfma(z, h - n, n);                                // h' = n + z*(h-n)
}

__global__ __launch_bounds__(256) void gru_fused(
    const float* __restrict__ inputs,   // (B, 2)
    const float* __restrict__ labels,   // (B, 8, 2)
    const float* __restrict__ w_ih,     // (2, 6, 2)
    const float* __restrict__ w_hh,     // (2, 6, 2)
    const float* __restrict__ b_ih,     // (2, 6)
    float* __restrict__ out,            // (B, 8, 2) + loss at [B*16]
    unsigned int* __restrict__ counter, // zeroed per call
    float* __restrict__ partials,       // (gridDim.x)
    int ne, double inv_n)
{
    __shared__ float lds[256 * 17];     // 17408 B; odd stride -> <=2-way conflicts
    const int tid = threadIdx.x;
    const int e0  = blockIdx.x * 512 + tid;   // phase-A element
    const int e1  = e0 + 256;                 // phase-B element

    const float2 xA = reinterpret_cast<const float2*>(inputs)[e0];
    const float2 xB = reinterpret_cast<const float2*>(inputs)[e1];

    // Wave-uniform packed weights (diag/anti-diag 2x2 matvec form), with
    // activation scales folded: p=0 (r), p=1 (z): -log2(e); p=2 (n): -2log2(e).
    v2f wihA[2][3], wihB[2][3], whhA[2][3], whhB[2][3], bpk[2][3];
#pragma unroll
    for (int g = 0; g < 2; ++g) {
#pragma unroll
        for (int p = 0; p < 3; ++p) {
            const float hf = (p < 2) ? -1.442695040888963f : -2.885390081777927f;
            const int r0 = g * 12 + (2 * p) * 2;
            const int r1 = g * 12 + (2 * p + 1) * 2;
            wihA[g][p] = v2(w_ih[r0 + 0] * hf, w_ih[r1 + 1] * hf);
            wihB[g][p] = v2(w_ih[r0 + 1] * hf, w_ih[r1 + 0] * hf);
            whhA[g][p] = v2(w_hh[r0 + 0] * hf, w_hh[r1 + 1] * hf);
            whhB[g][p] = v2(w_hh[r0 + 1] * hf, w_hh[r1 + 0] * hf);
            bpk[g][p]  = v2(b_ih[g * 6 + 2 * p] * hf, b_ih[g * 6 + 2 * p + 1] * hf);
        }
    }

    // Two independent recurrence chains (ILP-2 -> independent trans chains).
    v2f hA[2] = { vbc(0.0f), vbc(0.0f) }, hB[2] = { vbc(0.0f), vbc(0.0f) };
    v2f oA = v2(xA.x, xA.y), oB = v2(xB.x, xB.y);
    v2f resA[8], resB[8];

#pragma unroll
    for (int t = 0; t < 8; ++t) {
#pragma unroll
        for (int g = 0; g < 2; ++g) {
            hA[g] = gru_cell(oA, hA[g], wihA[g], wihB[g], whhA[g], whhB[g], bpk[g]);
            oA = hA[g];
            hB[g] = gru_cell(oB, hB[g], wihA[g], wihB[g], whhA[g], whhB[g], bpk[g]);
            oB = hB[g];
        }
        resA[t] = oA;
        resB[t] = oB;
    }

    // ---- epilogue: dense label loads, then two LDS transpose phases ----
    const v4f* labd = reinterpret_cast<const v4f*>(labels)
                    + (size_t)blockIdx.x * 2048 + tid;
    v4f labA[4], labB[4];
#pragma unroll
    for (int c = 0; c < 4; ++c) labA[c] = labd[c * 256];
#pragma unroll
    for (int c = 0; c < 4; ++c) labB[c] = labd[1024 + c * 256];

    v4f* outd = reinterpret_cast<v4f*>(out) + (size_t)blockIdx.x * 2048 + tid;
    float lsum = 0.0f;

    // Phase A: elements [blk*512, blk*512+256)
#pragma unroll
    for (int q = 0; q < 8; ++q) {
        lds[tid * 17 + 2 * q + 0] = resA[q].x;
        lds[tid * 17 + 2 * q + 1] = resA[q].y;
    }
    __syncthreads();
#pragma unroll
    for (int c = 0; c < 4; ++c) {
        const int f4   = c * 256 + tid;
        const int base = (f4 >> 2) * 17 + (f4 & 3) * 4;
        v4f ov;
        ov.x = lds[base + 0]; ov.y = lds[base + 1];
        ov.z = lds[base + 2]; ov.w = lds[base + 3];
        __builtin_nontemporal_store(ov, &outd[c * 256]);
        const v4f d = ov - labA[c];
        lsum += (d.x * d.x + d.y * d.y) + (d.z * d.z + d.w * d.w);
    }
    __syncthreads();

    // Phase B: elements [blk*512+256, blk*512+512)
#pragma unroll
    for (int q = 0; q < 8; ++q) {
        lds[tid * 17 + 2 * q + 0] = resB[q].x;
        lds[tid * 17 + 2 * q + 1] = resB[q].y;
    }
    __syncthreads();
#pragma unroll
    for (int c = 0; c < 4; ++c) {
        const int f4   = c * 256 + tid;
        const int base = (f4 >> 2) * 17 + (f4 & 3) * 4;
        v4f ov;
        ov.x = lds[base + 0]; ov.y = lds[base + 1];
        ov.z = lds[base + 2]; ov.w = lds[base + 3];
        __builtin_nontemporal_store(ov, &outd[1024 + c * 256]);
        const v4f d = ov - labB[c];
        lsum += (d.x * d.x + d.y * d.y) + (d.z * d.z + d.w * d.w);
    }

    // ---- block reduction -> agent-scope partial + last-block-done loss ----
#pragma unroll
    for (int off = 32; off > 0; off >>= 1)
        lsum += __shfl_down(lsum, off, 64);
    __shared__ float wsum[4];
    __shared__ int is_last;
    const int lane = tid & 63;
    const int wid  = tid >> 6;
    if (lane == 0) wsum[wid] = lsum;
    __syncthreads();
    if (tid == 0) {
        const float s = (wsum[0] + wsum[1]) + (wsum[2] + wsum[3]);
        // Agent-scope store: lands at LLC, visible to all XCDs.
        __hip_atomic_store(&partials[blockIdx.x], s,
                           __ATOMIC_RELAXED, __HIP_MEMORY_SCOPE_AGENT);
        const unsigned int old =
            __hip_atomic_fetch_add(counter, 1u,
                                   __ATOMIC_ACQ_REL, __HIP_MEMORY_SCOPE_AGENT);
        is_last = (old == gridDim.x - 1) ? 1 : 0;
    }
    __syncthreads();

    if (is_last) {
        const int nblk = gridDim.x;
        float s = 0.0f;
        for (int i = tid; i < nblk; i += 256)
            s += __hip_atomic_load(&partials[i],
                                   __ATOMIC_RELAXED, __HIP_MEMORY_SCOPE_AGENT);
#pragma unroll
        for (int off = 32; off > 0; off >>= 1)
            s += __shfl_down(s, off, 64);
        __shared__ float w2[4];
        if (lane == 0) w2[wid] = s;
        __syncthreads();
        if (tid == 0) {
            const double tot = (double)w2[0] + (double)w2[1]
                             + (double)w2[2] + (double)w2[3];
            out[ne] = (float)(tot * inv_n);
        }
    }
}

extern "C" void kernel_launch(void* const* d_in, const int* in_sizes, int n_in,
                              void* d_out, int out_size, void* d_ws, size_t ws_size,
                              hipStream_t stream) {
    const float* inputs = (const float*)d_in[0];
    const float* labels = (const float*)d_in[1];
    const float* w_ih   = (const float*)d_in[2];
    const float* w_hh   = (const float*)d_in[3];
    const float* b_ih   = (const float*)d_in[4];
    float* out = (float*)d_out;

    unsigned int* counter = (unsigned int*)d_ws;
    float* partials = (float*)((char*)d_ws + 256);

    const int B    = in_sizes[0] / 2;   // inputs is (B, H=2)
    const int NE   = B * 16;            // B*T*H ret elements
    const int grid = B / 512;           // 2 elements per thread

    hipMemsetAsync(d_ws, 0, 256, stream);   // zero the done-counter each call

    gru_fused<<<grid, 256, 0, stream>>>(inputs, labels, w_ih, w_hh, b_ih,
                                        out, counter, partials,
                                        NE, 1.0 / (double)NE);
}

// Round 15
// 57.705 us; speedup vs baseline: 3.5139x; 3.5139x over previous
//
#include <hip/hip_runtime.h>

// GRU stacked: G=2 layers, H=2, T=8, B=2097152.
// Round-15 = EXACT restore of round-8 (59.2us best). All later levers
// isolated null/negative: pair-rcp (r10), plain stores (r11), LDS prefetch +
// phase split (r12), 1-elem/thread occupancy probe (r13), fused last-block
// reduce (r14, catastrophic: per-block ACQ_REL agent atomic serializes L2
// maintenance against the NT store stream).
//   sigma(x') = rcp(1+exp2(x')), x' = -log2(e)*x (scale folded into W);
//   tanh via x' = -2log2(e)*x, 2*sig-1. Trans-pipe activations; ILP-2;
//   epilogue label loads; LDS transpose; NT dense stores; per-block
//   partials + tiny second reduce kernel (plain stores, no atomics).

typedef float v2f __attribute__((ext_vector_type(2)));
typedef float v4f __attribute__((ext_vector_type(4)));

__device__ __forceinline__ v2f v2(float a, float b) { v2f r; r.x = a; r.y = b; return r; }
__device__ __forceinline__ v2f vbc(float a) { return v2(a, a); }
__device__ __forceinline__ v2f vswap(v2f a) { return __builtin_shufflevector(a, a, 1, 0); }
__device__ __forceinline__ v2f vfma(v2f a, v2f b, v2f c) { return __builtin_elementwise_fma(a, b, c); }

// rcp(1+exp2(y)) per component: 2 exp2 + 2 rcp (trans), saturation-safe.
__device__ __forceinline__ v2f sig2(v2f y) {
    v2f e;
    e.x = __builtin_amdgcn_exp2f(y.x);
    e.y = __builtin_amdgcn_exp2f(y.y);
    const v2f d = e + vbc(1.0f);
    v2f q;
    q.x = __builtin_amdgcn_rcpf(d.x);
    q.y = __builtin_amdgcn_rcpf(d.y);
    return q;
}

// One GRU cell; weights pre-scaled: r/z rows by -log2(e), n rows by -2log2(e).
__device__ __forceinline__ v2f gru_cell(v2f o, v2f h,
    const v2f wihA[3], const v2f wihB[3],
    const v2f whhA[3], const v2f whhB[3], const v2f bpk[3])
{
    const v2f os = vswap(o);
    const v2f hs = vswap(h);
    v2f rin = vfma(wihA[0], o,
              vfma(wihB[0], os,
              vfma(whhA[0], h,
              vfma(whhB[0], hs, bpk[0]))));
    v2f zin = vfma(wihA[1], o,
              vfma(wihB[1], os,
              vfma(whhA[1], h,
              vfma(whhB[1], hs, bpk[1]))));
    v2f gin = vfma(wihA[2], o, vfma(wihB[2], os, bpk[2]));   // pre-scaled
    v2f ghn = vfma(whhA[2], h, whhB[2] * hs);                // pre-scaled

    const v2f r = sig2(rin);
    const v2f z = sig2(zin);
    const v2f q = sig2(vfma(r, ghn, gin));
    const v2f n = vfma(vbc(2.0f), q, vbc(-1.0f));            // tanh
    return vfma(z, h - n, n);                                // h' = n + z*(h-n)
}

__global__ __launch_bounds__(256) void gru_fused(
    const float* __restrict__ inputs,   // (B, 2)
    const float* __restrict__ labels,   // (B, 8, 2)
    const float* __restrict__ w_ih,     // (2, 6, 2)
    const float* __restrict__ w_hh,     // (2, 6, 2)
    const float* __restrict__ b_ih,     // (2, 6)
    float* __restrict__ out,            // (B, 8, 2)
    float* __restrict__ partials)       // (gridDim.x)
{
    __shared__ float lds[256 * 17];     // 17408 B; odd stride -> <=2-way conflicts
    const int tid = threadIdx.x;
    const int e0  = blockIdx.x * 512 + tid;   // phase-A element
    const int e1  = e0 + 256;                 // phase-B element

    const float2 xA = reinterpret_cast<const float2*>(inputs)[e0];
    const float2 xB = reinterpret_cast<const float2*>(inputs)[e1];

    // Wave-uniform packed weights (diag/anti-diag 2x2 matvec form), with
    // activation scales folded: p=0 (r), p=1 (z): -log2(e); p=2 (n): -2log2(e).
    v2f wihA[2][3], wihB[2][3], whhA[2][3], whhB[2][3], bpk[2][3];
#pragma unroll
    for (int g = 0; g < 2; ++g) {
#pragma unroll
        for (int p = 0; p < 3; ++p) {
            const float hf = (p < 2) ? -1.442695040888963f : -2.885390081777927f;
            const int r0 = g * 12 + (2 * p) * 2;
            const int r1 = g * 12 + (2 * p + 1) * 2;
            wihA[g][p] = v2(w_ih[r0 + 0] * hf, w_ih[r1 + 1] * hf);
            wihB[g][p] = v2(w_ih[r0 + 1] * hf, w_ih[r1 + 0] * hf);
            whhA[g][p] = v2(w_hh[r0 + 0] * hf, w_hh[r1 + 1] * hf);
            whhB[g][p] = v2(w_hh[r0 + 1] * hf, w_hh[r1 + 0] * hf);
            bpk[g][p]  = v2(b_ih[g * 6 + 2 * p] * hf, b_ih[g * 6 + 2 * p + 1] * hf);
        }
    }

    // Two independent recurrence chains (ILP-2 -> independent trans chains).
    v2f hA[2] = { vbc(0.0f), vbc(0.0f) }, hB[2] = { vbc(0.0f), vbc(0.0f) };
    v2f oA = v2(xA.x, xA.y), oB = v2(xB.x, xB.y);
    v2f resA[8], resB[8];

#pragma unroll
    for (int t = 0; t < 8; ++t) {
#pragma unroll
        for (int g = 0; g < 2; ++g) {
            hA[g] = gru_cell(oA, hA[g], wihA[g], wihB[g], whhA[g], whhB[g], bpk[g]);
            oA = hA[g];
            hB[g] = gru_cell(oB, hB[g], wihA[g], wihB[g], whhA[g], whhB[g], bpk[g]);
            oB = hB[g];
        }
        resA[t] = oA;
        resB[t] = oB;
    }

    // ---- epilogue: dense label loads, then two LDS transpose phases ----
    const v4f* labd = reinterpret_cast<const v4f*>(labels)
                    + (size_t)blockIdx.x * 2048 + tid;
    v4f labA[4], labB[4];
#pragma unroll
    for (int c = 0; c < 4; ++c) labA[c] = labd[c * 256];
#pragma unroll
    for (int c = 0; c < 4; ++c) labB[c] = labd[1024 + c * 256];

    v4f* outd = reinterpret_cast<v4f*>(out) + (size_t)blockIdx.x * 2048 + tid;
    float lsum = 0.0f;

    // Phase A: elements [blk*512, blk*512+256)
#pragma unroll
    for (int q = 0; q < 8; ++q) {
        lds[tid * 17 + 2 * q + 0] = resA[q].x;
        lds[tid * 17 + 2 * q + 1] = resA[q].y;
    }
    __syncthreads();
#pragma unroll
    for (int c = 0; c < 4; ++c) {
        const int f4   = c * 256 + tid;
        const int base = (f4 >> 2) * 17 + (f4 & 3) * 4;
        v4f ov;
        ov.x = lds[base + 0]; ov.y = lds[base + 1];
        ov.z = lds[base + 2]; ov.w = lds[base + 3];
        __builtin_nontemporal_store(ov, &outd[c * 256]);
        const v4f d = ov - labA[c];
        lsum += (d.x * d.x + d.y * d.y) + (d.z * d.z + d.w * d.w);
    }
    __syncthreads();

    // Phase B: elements [blk*512+256, blk*512+512)
#pragma unroll
    for (int q = 0; q < 8; ++q) {
        lds[tid * 17 + 2 * q + 0] = resB[q].x;
        lds[tid * 17 + 2 * q + 1] = resB[q].y;
    }
    __syncthreads();
#pragma unroll
    for (int c = 0; c < 4; ++c) {
        const int f4   = c * 256 + tid;
        const int base = (f4 >> 2) * 17 + (f4 & 3) * 4;
        v4f ov;
        ov.x = lds[base + 0]; ov.y = lds[base + 1];
        ov.z = lds[base + 2]; ov.w = lds[base + 3];
        __builtin_nontemporal_store(ov, &outd[1024 + c * 256]);
        const v4f d = ov - labB[c];
        lsum += (d.x * d.x + d.y * d.y) + (d.z * d.z + d.w * d.w);
    }

    // Block reduction -> ONE plain store per block (no atomics).
#pragma unroll
    for (int off = 32; off > 0; off >>= 1)
        lsum += __shfl_down(lsum, off, 64);
    __shared__ float wsum[4];
    const int lane = tid & 63;
    const int wid  = tid >> 6;
    if (lane == 0) wsum[wid] = lsum;
    __syncthreads();
    if (tid == 0)
        partials[blockIdx.x] = (wsum[0] + wsum[1]) + (wsum[2] + wsum[3]);
}

__global__ __launch_bounds__(1024) void gru_loss_reduce(
    const v4f* __restrict__ partials4, int n4,
    float* __restrict__ loss_out, double inv_n)
{
    float s = 0.0f;
    for (int i = threadIdx.x; i < n4; i += 1024) {
        const v4f p = partials4[i];
        s += (p.x + p.y) + (p.z + p.w);
    }
#pragma unroll
    for (int off = 32; off > 0; off >>= 1)
        s += __shfl_down(s, off, 64);
    __shared__ float wsum[16];
    const int lane = threadIdx.x & 63;
    const int wid  = threadIdx.x >> 6;
    if (lane == 0) wsum[wid] = s;
    __syncthreads();
    if (threadIdx.x == 0) {
        double tot = 0.0;
#pragma unroll
        for (int i = 0; i < 16; ++i) tot += (double)wsum[i];
        *loss_out = (float)(tot * inv_n);
    }
}

extern "C" void kernel_launch(void* const* d_in, const int* in_sizes, int n_in,
                              void* d_out, int out_size, void* d_ws, size_t ws_size,
                              hipStream_t stream) {
    const float* inputs = (const float*)d_in[0];
    const float* labels = (const float*)d_in[1];
    const float* w_ih   = (const float*)d_in[2];
    const float* w_hh   = (const float*)d_in[3];
    const float* b_ih   = (const float*)d_in[4];
    float* out      = (float*)d_out;
    float* partials = (float*)d_ws;

    const int B    = in_sizes[0] / 2;   // inputs is (B, H=2)
    const int NE   = B * 16;            // B*T*H ret elements
    const int grid = B / 512;           // 2 elements per thread

    gru_fused<<<grid, 256, 0, stream>>>(inputs, labels, w_ih, w_hh, b_ih,
                                        out, partials);
    gru_loss_reduce<<<1, 1024, 0, stream>>>((const v4f*)partials, grid / 4,
                                            out + NE, 1.0 / (double)NE);
}